// Round 10
// baseline (291.049 us; speedup 1.0000x reference)
//
#include <hip/hip_runtime.h>
#include <hip/hip_bf16.h>
#include <math.h>

#define EMBED   768
#define NHEADS  12
#define HD      64
#define HIDDEN  3072
#define SEQ     2048
#define BATCH   2
#define ROWS    (BATCH*SEQ)   // 4096

// exp(s/8) == exp2(s * 0.125*log2(e)); folded into Q at qkv-GEMM epilogue.
#define QSCALE  0.1803368801111204f

typedef __bf16 bf16_t;
typedef __attribute__((ext_vector_type(8))) __bf16 bf16x8;
typedef __attribute__((ext_vector_type(4))) float f32x4;

static __device__ __forceinline__ f32x4 mfma16(bf16x8 a, bf16x8 b, f32x4 c) {
  return __builtin_amdgcn_mfma_f32_16x16x32_bf16(a, b, c, 0, 0, 0);
}

// exp2 as a single v_exp_f32 WITH compiler-managed trans-op hazards.
#if __has_builtin(__builtin_amdgcn_exp2f)
static __device__ __forceinline__ float fast_exp2(float x) {
  return __builtin_amdgcn_exp2f(x);
}
#else
static __device__ __forceinline__ float fast_exp2(float x) { return exp2f(x); }
#endif

// async global->LDS, 16B per lane. LDS dest = wave-uniform base + lane*16.
typedef __attribute__((address_space(1))) const void gas_void;
typedef __attribute__((address_space(3))) void las_void;
static __device__ __forceinline__ void gll16(const void* g, void* l) {
  __builtin_amdgcn_global_load_lds((gas_void*)g, (las_void*)l, 16, 0, 0);
}

// ---------------------------------------------------------------------------
// Prep: all 4 weight transposes (fp32 [R,C] -> bf16 [C,R]) + LN1, ONE launch.
// Blocks [0,6912): transpose tiles. Blocks [6912,6912+4096): LN1 rows.
// ---------------------------------------------------------------------------
__global__ __launch_bounds__(256) void prep_kernel(
    const float* __restrict__ w0, bf16_t* __restrict__ o0,   // qkv  768x2304
    const float* __restrict__ w1, bf16_t* __restrict__ o1,   // proj 768x768
    const float* __restrict__ w2, bf16_t* __restrict__ o2,   // fc1  768x3072
    const float* __restrict__ w3, bf16_t* __restrict__ o3,   // fc2  3072x768
    const float* __restrict__ x,  const float* __restrict__ g,
    const float* __restrict__ bt, bf16_t* __restrict__ lnout)
{
  __shared__ float tile[32][33];
  __shared__ float red[8];
  int lin = blockIdx.x;
  if (lin < 6912) {
    const float* in; bf16_t* out; int R, C, bx, by;
    if (lin < 1728)      { in = w0; out = o0; R = 768;  C = 2304; bx = lin % 72; by = lin / 72; }
    else if (lin < 2304) { in = w1; out = o1; R = 768;  C = 768;  lin -= 1728; bx = lin % 24; by = lin / 24; }
    else if (lin < 4608) { in = w2; out = o2; R = 768;  C = 3072; lin -= 2304; bx = lin % 96; by = lin / 96; }
    else                 { in = w3; out = o3; R = 3072; C = 768;  lin -= 4608; bx = lin % 24; by = lin / 24; }
    int c0 = bx * 32, r0 = by * 32;
    int tx = threadIdx.x & 31, ty = threadIdx.x >> 5;
    #pragma unroll
    for (int p = 0; p < 4; ++p) {
      int r = ty + p * 8;
      tile[r][tx] = in[(size_t)(r0 + r) * C + c0 + tx];
    }
    __syncthreads();
    #pragma unroll
    for (int p = 0; p < 4; ++p) {
      int cc = ty + p * 8;
      out[(size_t)(c0 + cc) * R + r0 + tx] = (bf16_t)tile[tx][cc];
    }
    return;
  }
  // ---- LayerNorm rows ----
  int row = lin - 6912;
  int tid = threadIdx.x;
  const float* xr = x + (size_t)row * EMBED;
  float v0 = xr[tid], v1 = xr[tid + 256], v2 = xr[tid + 512];
  float s  = v0 + v1 + v2;
  float s2 = v0*v0 + v1*v1 + v2*v2;
  #pragma unroll
  for (int o = 32; o >= 1; o >>= 1) {
    s  += __shfl_xor(s,  o, 64);
    s2 += __shfl_xor(s2, o, 64);
  }
  int wave = tid >> 6, lane = tid & 63;
  if (lane == 0) { red[wave] = s; red[wave + 4] = s2; }
  __syncthreads();
  s  = red[0] + red[1] + red[2] + red[3];
  s2 = red[4] + red[5] + red[6] + red[7];
  float mu  = s * (1.0f / EMBED);
  float var = s2 * (1.0f / EMBED) - mu * mu;
  float rs  = rsqrtf(var + 1e-5f);
  bf16_t* orow = lnout + (size_t)row * EMBED;
  orow[tid]       = (bf16_t)((v0 - mu) * rs * g[tid]       + bt[tid]);
  orow[tid + 256] = (bf16_t)((v1 - mu) * rs * g[tid + 256] + bt[tid + 256]);
  orow[tid + 512] = (bf16_t)((v2 - mu) * rs * g[tid + 512] + bt[tid + 512]);
}

// ---------------------------------------------------------------------------
// Standalone LayerNorm (for ln2): one block per row. fp32 in -> bf16 out.
// ---------------------------------------------------------------------------
__global__ __launch_bounds__(256) void ln_kernel(
    const float* __restrict__ x, const float* __restrict__ g,
    const float* __restrict__ bt, bf16_t* __restrict__ out)
{
  int row = blockIdx.x;
  int tid = threadIdx.x;
  const float* xr = x + (size_t)row * EMBED;
  float v0 = xr[tid], v1 = xr[tid + 256], v2 = xr[tid + 512];
  float s  = v0 + v1 + v2;
  float s2 = v0*v0 + v1*v1 + v2*v2;
  #pragma unroll
  for (int o = 32; o >= 1; o >>= 1) {
    s  += __shfl_xor(s,  o, 64);
    s2 += __shfl_xor(s2, o, 64);
  }
  __shared__ float red[8];
  int wave = tid >> 6, lane = tid & 63;
  if (lane == 0) { red[wave] = s; red[wave + 4] = s2; }
  __syncthreads();
  s  = red[0] + red[1] + red[2] + red[3];
  s2 = red[4] + red[5] + red[6] + red[7];
  float mu  = s * (1.0f / EMBED);
  float var = s2 * (1.0f / EMBED) - mu * mu;
  float rs  = rsqrtf(var + 1e-5f);
  bf16_t* orow = out + (size_t)row * EMBED;
  orow[tid]       = (bf16_t)((v0 - mu) * rs * g[tid]       + bt[tid]);
  orow[tid + 256] = (bf16_t)((v1 - mu) * rs * g[tid + 256] + bt[tid + 256]);
  orow[tid + 512] = (bf16_t)((v2 - mu) * rs * g[tid + 512] + bt[tid + 512]);
}

// ---------------------------------------------------------------------------
// GEMM: out[M,N] = epi(A[M,K] @ WT[N,K]^T + bias [+res]).  BK=64.
// 128xBN tile, 1D grid, XCD-aware swizzle. global_load_lds staging, XOR-LDS.
// MODE 1: bf16+GELU. MODE 2: fp32+residual store. MODE 3 (qkv): bf16; n<768
// scaled by QSCALE -> qkv buf; 768<=n<1536 (K) -> qkv buf; n>=1536 (V) ->
// written TRANSPOSED into vt[bh][d][l]. MODE 4: split-K=2, fp32 atomicAdd
// into outp (which already holds the residual); khalf==0 adds bias.
// ---------------------------------------------------------------------------
template<int MODE, int BN>
__global__ __launch_bounds__(256) void gemm_kernel(
    const bf16_t* __restrict__ A, const bf16_t* __restrict__ WT,
    const float* __restrict__ bias, const float* __restrict__ res,
    void* __restrict__ outp, bf16_t* __restrict__ vt, int N, int K)
{
  constexpr int JT = BN / 32;              // n-subtiles per wave
  __shared__ bf16_t As[128 * 64];
  __shared__ bf16_t Bs[BN * 64];
  int tid = threadIdx.x;
  int lane = tid & 63, wave = tid >> 6;
  int l15 = lane & 15, quad = lane >> 4;
  int wm = wave >> 1, wn = wave & 1;

  int Nn = N / BN;
  int lin = blockIdx.x;
  int khalf = 0, k_lo = 0, k_hi = K;
  if (MODE == 4) { khalf = lin & 1; lin >>= 1; k_lo = khalf * (K / 2); k_hi = k_lo + K / 2; }
  int bm = (lin & 7) + 8 * ((lin >> 3) / Nn);
  int bn = (lin >> 3) % Nn;
  int m0 = bm * 128, n0 = bn * BN;

  f32x4 acc[4][JT];
  #pragma unroll
  for (int i = 0; i < 4; ++i)
    #pragma unroll
    for (int j = 0; j < JT; ++j)
      acc[i][j] = (f32x4){0.f, 0.f, 0.f, 0.f};

  int grow = lane >> 3;                     // 0..7
  int gcol = ((lane & 7) ^ grow) * 8;       // logical chunk for phys slot
  const bf16_t* abase = A  + (size_t)(m0 + wave * 32 + grow) * K + gcol;
  const bf16_t* bbase = WT + (size_t)(n0 + wave * (BN / 4) + grow) * K + gcol;
  int swk = l15 & 7;

  for (int k0 = k_lo; k0 < k_hi; k0 += 64) {
    #pragma unroll
    for (int a = 0; a < 4; ++a)
      gll16(abase + (size_t)a * 8 * K + k0, &As[(wave * 32 + a * 8) * 64]);
    #pragma unroll
    for (int a = 0; a < BN / 32; ++a)
      gll16(bbase + (size_t)a * 8 * K + k0, &Bs[(wave * (BN / 4) + a * 8) * 64]);
    __syncthreads();

    #pragma unroll
    for (int g = 0; g < 2; ++g) {
      bf16x8 af[4], bfr[JT];
      #pragma unroll
      for (int i = 0; i < 4; ++i)
        af[i] = *(const bf16x8*)
            &As[(wm * 64 + i * 16 + l15) * 64 + (((g * 4 + quad) ^ swk) * 8)];
      #pragma unroll
      for (int j = 0; j < JT; ++j)
        bfr[j] = *(const bf16x8*)
            &Bs[(wn * (BN / 2) + j * 16 + l15) * 64 + (((g * 4 + quad) ^ swk) * 8)];
      #pragma unroll
      for (int i = 0; i < 4; ++i)
        #pragma unroll
        for (int j = 0; j < JT; ++j)
          acc[i][j] = mfma16(af[i], bfr[j], acc[i][j]);
    }
    __syncthreads();
  }

  #pragma unroll
  for (int i = 0; i < 4; ++i) {
    int mbase = m0 + wm * 64 + i * 16 + quad * 4;
    #pragma unroll
    for (int j = 0; j < JT; ++j) {
      int n = n0 + wn * (BN / 2) + j * 16 + l15;
      float bn_ = (MODE == 4 && khalf != 0) ? 0.f : bias[n];
      if (MODE == 3 && n >= 1536) {
        // V output -> vt[bh][d][l], packed 4 consecutive l per lane
        int dcol = n - 1536;
        int hh = dcol >> 6, dd = dcol & 63;
        int bsel = mbase >> 11, l = mbase & 2047;
        union { bf16_t b4[4]; uint2 u; } pk;
        #pragma unroll
        for (int r = 0; r < 4; ++r)
          pk.b4[r] = (bf16_t)(acc[i][j][r] + bn_);
        *(uint2*)&vt[(((size_t)bsel * NHEADS + hh) * HD + dd) * SEQ + l] = pk.u;
        continue;
      }
      #pragma unroll
      for (int r = 0; r < 4; ++r) {
        size_t idx = (size_t)(mbase + r) * N + n;
        float v = acc[i][j][r] + bn_;
        if (MODE == 1) v = 0.5f * v * (1.0f + erff(v * 0.70710678118654752f));
        if (MODE == 3 && n < 768) v *= QSCALE;
        if (MODE == 2) {
          v += res[idx];
          ((float*)outp)[idx] = v;
        } else if (MODE == 4) {
          atomicAdd((float*)outp + idx, v);
        } else {
          ((bf16_t*)outp)[idx] = (bf16_t)v;
        }
      }
    }
  }
}

// ---------------------------------------------------------------------------
// Flash attention: 128 q-rows/block, kv-split waves, barrier-free dbuf loop.
// R10 changes: (1) ptile rotates over 4 slots (qi&3) so the per-qi
// QK->exp->LDS->PV chains pipeline instead of serializing on LDS WAR;
// (2) V B-frags register-prefetched one iteration ahead (vmcnt(8) at top
// covers only the PREVIOUS iteration's 4 V loads + 4 K gll16s);
// (3) 1D grid with XCD head-pinning: each XCD's L2 serves 3 heads' K/V.
// ---------------------------------------------------------------------------
__global__ __launch_bounds__(256, 2) void attn_kernel(
    const bf16_t* __restrict__ qkv, const bf16_t* __restrict__ vt,
    bf16_t* __restrict__ attnout)
{
  // per wave: 2 bufs x K 2048 elems = 8KB; + 4 ptile slots x 640 elems
  __attribute__((aligned(16))) __shared__ bf16_t smem[4 * 4096 + 4 * 4 * 640];
  __shared__ float dsumf[4][128];

  // XCD head-pinning: 48 blocks per XCD = 3 heads x 16 q-tiles
  int lin = blockIdx.x;            // 0..383, XCD = lin & 7 (round-robin)
  int slot = lin >> 3;             // 0..47
  int bh = (lin & 7) * 3 + slot / 16;   // 0..23
  int qt = slot & 15;
  int b = bh / NHEADS, h = bh % NHEADS;

  int tid = threadIdx.x;
  int wave = tid >> 6, lane = tid & 63;
  int l15 = lane & 15, quad = lane >> 4;
  int q0 = qt * 128;

  bf16_t* wbase = smem + wave * 4096;           // [buf][K 2048]
  bf16_t* pt0   = smem + 16384 + wave * 2560;   // 4 slots x [16 q][stride 40]

  // Q B-frags (pre-scaled by QSCALE): n=q=l15, k=d=quad*8+j (+32 frag 1)
  bf16x8 bq[8][2];
  #pragma unroll
  for (int qi = 0; qi < 8; ++qi) {
    const bf16_t* qrow = qkv + (size_t)(b * SEQ + q0 + qi * 16 + l15) * 2304
                             + h * HD + quad * 8;
    bq[qi][0] = *(const bf16x8*)qrow;
    bq[qi][1] = *(const bf16x8*)(qrow + 32);
  }
  // drain Q loads so the in-loop vmcnt(8) tracks only staging/V ops
  __asm__ volatile("s_waitcnt vmcnt(0)" ::: "memory");

  f32x4 accO[8][4];
  #pragma unroll
  for (int qi = 0; qi < 8; ++qi)
    #pragma unroll
    for (int t2 = 0; t2 < 4; ++t2)
      accO[qi][t2] = (f32x4){0.f, 0.f, 0.f, 0.f};
  float lpart[8] = {};

  // K staging lane mapping (wave-private tile, coalesced 16B/lane)
  int krow_l = lane >> 3;
  int kchunk = ((lane & 7) ^ krow_l) * 8;
  const bf16_t* ksrc0 = qkv + (size_t)(b * SEQ + wave * 32 + krow_l) * 2304
                            + 768 + h * HD + kchunk;
  // V B-frag source: n=d=t2*16+l15, k=kv=quad*8+j
  const bf16_t* vb0 = vt + ((size_t)bh * HD + l15) * SEQ + wave * 32 + quad * 8;

  constexpr int NIT = SEQ / 128;   // 16

  // prologue: stage K tile 0 into buf 0; load V frags for tile 0
  #pragma unroll
  for (int p = 0; p < 4; ++p)
    gll16(ksrc0 + (size_t)(p * 8) * 2304, wbase + p * 512);
  bf16x8 bv_cur[4];
  #pragma unroll
  for (int t2 = 0; t2 < 4; ++t2)
    bv_cur[t2] = *(const bf16x8*)(vb0 + (size_t)(t2 * 16) * SEQ);

  int cb = 0;
  for (int it = 0; it < NIT; ++it) {
    int kvn = ((it + 1) & (NIT - 1)) * 128;
    // prefetch NEXT V frags into registers (in flight across this iter)
    bf16x8 bv_nxt[4];
    #pragma unroll
    for (int t2 = 0; t2 < 4; ++t2)
      bv_nxt[t2] = *(const bf16x8*)(vb0 + (size_t)(t2 * 16) * SEQ + kvn);
    // prefetch NEXT K tile into other buffer
    {
      const bf16_t* ks = ksrc0 + (size_t)kvn * 2304;
      bf16_t* kb = wbase + (cb ^ 1) * 2048;
      #pragma unroll
      for (int p = 0; p < 4; ++p)
        gll16(ks + (size_t)(p * 8) * 2304, kb + p * 512);
    }
    // wait: all but the 8 just-issued ops done => current K tile (and
    // current V, loaded last iteration) complete; prefetch stays in flight
    __asm__ volatile("s_waitcnt vmcnt(8)" ::: "memory");

    const bf16_t* kb = wbase + cb * 2048;

    // K A-frags: m=kv=t*16+l15, k=d=(f*4+quad)*8+j ; swizzle phys=c^(l15&7)
    bf16x8 ak[2][2];
    #pragma unroll
    for (int t = 0; t < 2; ++t)
      #pragma unroll
      for (int f = 0; f < 2; ++f)
        ak[t][f] = *(const bf16x8*)
            &kb[(t * 16 + l15) * 64 + (((f * 4 + quad) ^ (l15 & 7)) * 8)];

    #pragma unroll
    for (int qi = 0; qi < 8; ++qi) {
      bf16_t* pt = pt0 + (qi & 3) * 640;     // rotate slots: 4 chains in flight
      #pragma unroll
      for (int t = 0; t < 2; ++t) {
        f32x4 s = (f32x4){0.f, 0.f, 0.f, 0.f};
        s = mfma16(ak[t][0], bq[qi][0], s);   // S^T: (kv=quad*4+r, q=l15)
        s = mfma16(ak[t][1], bq[qi][1], s);
        union { bf16_t b4[4]; uint2 u; } pk;
        float ls = 0.f;
        #pragma unroll
        for (int r = 0; r < 4; ++r) {
          float pv = fast_exp2(s[r]);
          ls += pv;
          pk.b4[r] = (bf16_t)pv;
        }
        lpart[qi] += ls;
        *(uint2*)&pt[l15 * 40 + t * 16 + quad * 4] = pk.u;
      }
      bf16x8 ap = *(const bf16x8*)&pt[l15 * 40 + quad * 8];
      #pragma unroll
      for (int t2 = 0; t2 < 4; ++t2)
        accO[qi][t2] = mfma16(ap, bv_cur[t2], accO[qi][t2]);
    }
    #pragma unroll
    for (int t2 = 0; t2 < 4; ++t2) bv_cur[t2] = bv_nxt[t2];
    cb ^= 1;
  }

  // denominators: lane holds partial for q=l15 over this wave's kv slices
  #pragma unroll
  for (int qi = 0; qi < 8; ++qi) {
    float l = lpart[qi];
    l += __shfl_xor(l, 16, 64);
    l += __shfl_xor(l, 32, 64);
    if (quad == 0) dsumf[wave][qi * 16 + l15] = l;
  }
  __syncthreads();   // waves done with private tiles; dsumf published

  float* slabf = (float*)smem;   // 4 slabs x 2048 f32 = 32 KB (K dbuf region)
  int rq = lane >> 3;            // 0..7
  int d0 = (lane & 7) * 8;

  for (int pass = 0; pass < 4; ++pass) {
    #pragma unroll
    for (int qi2 = 0; qi2 < 2; ++qi2) {
      int qi = pass * 2 + qi2;
      #pragma unroll
      for (int t2 = 0; t2 < 4; ++t2)
        #pragma unroll
        for (int r = 0; r < 4; ++r)
          slabf[wave * 2048 + (qi2 * 16 + quad * 4 + r) * 64 + t2 * 16 + l15]
              = accO[qi][t2][r];
    }
    __syncthreads();
    int q_loc = wave * 8 + rq;
    f32x4 o0 = (f32x4){0.f,0.f,0.f,0.f}, o1 = (f32x4){0.f,0.f,0.f,0.f};
    #pragma unroll
    for (int sw = 0; sw < 4; ++sw) {
      o0 += *(const f32x4*)&slabf[sw * 2048 + q_loc * 64 + d0];
      o1 += *(const f32x4*)&slabf[sw * 2048 + q_loc * 64 + d0 + 4];
    }
    int q_abs = pass * 32 + q_loc;
    float den = dsumf[0][q_abs] + dsumf[1][q_abs] + dsumf[2][q_abs] + dsumf[3][q_abs];
    float inv = 1.0f / den;
    bf16_t ob[8];
    #pragma unroll
    for (int j = 0; j < 4; ++j) {
      ob[j]     = (bf16_t)(o0[j] * inv);
      ob[j + 4] = (bf16_t)(o1[j] * inv);
    }
    *(uint4*)&attnout[(size_t)(b * SEQ + q0 + q_abs) * EMBED + h * HD + d0]
        = *(const uint4*)ob;
    if (pass < 3) __syncthreads();
  }
}

// ---------------------------------------------------------------------------
extern "C" void kernel_launch(void* const* d_in, const int* in_sizes, int n_in,
                              void* d_out, int out_size, void* d_ws, size_t ws_size,
                              hipStream_t stream) {
  (void)in_sizes; (void)n_in; (void)out_size; (void)ws_size;
  const float* x      = (const float*)d_in[0];
  const float* ln1_g  = (const float*)d_in[1];
  const float* ln1_b  = (const float*)d_in[2];
  const float* qkv_w  = (const float*)d_in[3];
  const float* qkv_b  = (const float*)d_in[4];
  const float* proj_w = (const float*)d_in[5];
  const float* proj_b = (const float*)d_in[6];
  const float* ln2_g  = (const float*)d_in[7];
  const float* ln2_b  = (const float*)d_in[8];
  const float* fc1_w  = (const float*)d_in[9];
  const float* fc1_b  = (const float*)d_in[10];
  const float* fc2_w  = (const float*)d_in[11];
  const float* fc2_b  = (const float*)d_in[12];
  float* out = (float*)d_out;

  char* p = (char*)d_ws;
  bf16_t* wqkvT  = (bf16_t*)p; p += (size_t)2304 * 768 * 2;
  bf16_t* wprojT = (bf16_t*)p; p += (size_t)768 * 768 * 2;
  bf16_t* wfc1T  = (bf16_t*)p; p += (size_t)3072 * 768 * 2;
  bf16_t* wfc2T  = (bf16_t*)p; p += (size_t)768 * 3072 * 2;
  bf16_t* hbuf   = (bf16_t*)p; p += (size_t)ROWS * 768 * 2;
  bf16_t* qkv    = (bf16_t*)p;          // dead after attention
  bf16_t* hid    = (bf16_t*)p; p += (size_t)ROWS * 3072 * 2;  // aliases qkv
  bf16_t* vt     = (bf16_t*)p; p += (size_t)BATCH * NHEADS * HD * SEQ * 2;
  bf16_t* attno  = (bf16_t*)p; p += (size_t)ROWS * 768 * 2;

  // weight prep + LN1 (one launch; no static state allowed)
  prep_kernel<<<6912 + ROWS, 256, 0, stream>>>(
      qkv_w, wqkvT, proj_w, wprojT, fc1_w, wfc1T, fc2_w, wfc2T,
      x, ln1_g, ln1_b, hbuf);

  // attention sublayer (qkv GEMM writes V directly transposed into vt)
  gemm_kernel<3,128><<<32 * (2304/128), 256, 0, stream>>>(
      hbuf, wqkvT, qkv_b, nullptr, qkv, vt, 2304, 768);
  attn_kernel<<<384, 256, 0, stream>>>(qkv, vt, attno);
  gemm_kernel<2,64><<<32 * (768/64), 256, 0, stream>>>(
      attno, wprojT, proj_b, x, out, nullptr, 768, 768);

  // FFN sublayer
  ln_kernel<<<ROWS, 256, 0, stream>>>(out, ln2_g, ln2_b, hbuf);
  gemm_kernel<1,128><<<32 * (3072/128), 256, 0, stream>>>(
      hbuf, wfc1T, fc1_b, nullptr, hid, nullptr, 3072, 768);
  gemm_kernel<4,64><<<2 * 32 * (768/64), 256, 0, stream>>>(
      hid, wfc2T, fc2_b, nullptr, out, nullptr, 768, 3072);
}

// Round 11
// 274.641 us; speedup vs baseline: 1.0597x; 1.0597x over previous
//
#include <hip/hip_runtime.h>
#include <hip/hip_bf16.h>
#include <math.h>

#define EMBED   768
#define NHEADS  12
#define HD      64
#define HIDDEN  3072
#define SEQ     2048
#define BATCH   2
#define ROWS    (BATCH*SEQ)   // 4096

// exp(s/8) == exp2(s * 0.125*log2(e)); folded into Q at qkv-GEMM epilogue.
#define QSCALE  0.1803368801111204f

typedef __bf16 bf16_t;
typedef __attribute__((ext_vector_type(8))) __bf16 bf16x8;
typedef __attribute__((ext_vector_type(4))) float f32x4;

static __device__ __forceinline__ f32x4 mfma16(bf16x8 a, bf16x8 b, f32x4 c) {
  return __builtin_amdgcn_mfma_f32_16x16x32_bf16(a, b, c, 0, 0, 0);
}

// exp2 as a single v_exp_f32 WITH compiler-managed trans-op hazards.
#if __has_builtin(__builtin_amdgcn_exp2f)
static __device__ __forceinline__ float fast_exp2(float x) {
  return __builtin_amdgcn_exp2f(x);
}
#else
static __device__ __forceinline__ float fast_exp2(float x) { return exp2f(x); }
#endif

#if __has_builtin(__builtin_amdgcn_rcpf)
static __device__ __forceinline__ float fast_rcp(float x) {
  return __builtin_amdgcn_rcpf(x);
}
#else
static __device__ __forceinline__ float fast_rcp(float x) { return 1.0f / x; }
#endif

// async global->LDS, 16B per lane. LDS dest = wave-uniform base + lane*16.
typedef __attribute__((address_space(1))) const void gas_void;
typedef __attribute__((address_space(3))) void las_void;
static __device__ __forceinline__ void gll16(const void* g, void* l) {
  __builtin_amdgcn_global_load_lds((gas_void*)g, (las_void*)l, 16, 0, 0);
}

// ---------------------------------------------------------------------------
// Prep: all 4 weight transposes (fp32 [R,C] -> bf16 [C,R]) + LN1, ONE launch.
// ---------------------------------------------------------------------------
__global__ __launch_bounds__(256) void prep_kernel(
    const float* __restrict__ w0, bf16_t* __restrict__ o0,   // qkv  768x2304
    const float* __restrict__ w1, bf16_t* __restrict__ o1,   // proj 768x768
    const float* __restrict__ w2, bf16_t* __restrict__ o2,   // fc1  768x3072
    const float* __restrict__ w3, bf16_t* __restrict__ o3,   // fc2  3072x768
    const float* __restrict__ x,  const float* __restrict__ g,
    const float* __restrict__ bt, bf16_t* __restrict__ lnout)
{
  __shared__ float tile[32][33];
  __shared__ float red[8];
  int lin = blockIdx.x;
  if (lin < 6912) {
    const float* in; bf16_t* out; int R, C, bx, by;
    if (lin < 1728)      { in = w0; out = o0; R = 768;  C = 2304; bx = lin % 72; by = lin / 72; }
    else if (lin < 2304) { in = w1; out = o1; R = 768;  C = 768;  lin -= 1728; bx = lin % 24; by = lin / 24; }
    else if (lin < 4608) { in = w2; out = o2; R = 768;  C = 3072; lin -= 2304; bx = lin % 96; by = lin / 96; }
    else                 { in = w3; out = o3; R = 3072; C = 768;  lin -= 4608; bx = lin % 24; by = lin / 24; }
    int c0 = bx * 32, r0 = by * 32;
    int tx = threadIdx.x & 31, ty = threadIdx.x >> 5;
    #pragma unroll
    for (int p = 0; p < 4; ++p) {
      int r = ty + p * 8;
      tile[r][tx] = in[(size_t)(r0 + r) * C + c0 + tx];
    }
    __syncthreads();
    #pragma unroll
    for (int p = 0; p < 4; ++p) {
      int cc = ty + p * 8;
      out[(size_t)(c0 + cc) * R + r0 + tx] = (bf16_t)tile[tx][cc];
    }
    return;
  }
  // ---- LayerNorm rows ----
  int row = lin - 6912;
  int tid = threadIdx.x;
  const float* xr = x + (size_t)row * EMBED;
  float v0 = xr[tid], v1 = xr[tid + 256], v2 = xr[tid + 512];
  float s  = v0 + v1 + v2;
  float s2 = v0*v0 + v1*v1 + v2*v2;
  #pragma unroll
  for (int o = 32; o >= 1; o >>= 1) {
    s  += __shfl_xor(s,  o, 64);
    s2 += __shfl_xor(s2, o, 64);
  }
  int wave = tid >> 6, lane = tid & 63;
  if (lane == 0) { red[wave] = s; red[wave + 4] = s2; }
  __syncthreads();
  s  = red[0] + red[1] + red[2] + red[3];
  s2 = red[4] + red[5] + red[6] + red[7];
  float mu  = s * (1.0f / EMBED);
  float var = s2 * (1.0f / EMBED) - mu * mu;
  float rs  = rsqrtf(var + 1e-5f);
  bf16_t* orow = lnout + (size_t)row * EMBED;
  orow[tid]       = (bf16_t)((v0 - mu) * rs * g[tid]       + bt[tid]);
  orow[tid + 256] = (bf16_t)((v1 - mu) * rs * g[tid + 256] + bt[tid + 256]);
  orow[tid + 512] = (bf16_t)((v2 - mu) * rs * g[tid + 512] + bt[tid + 512]);
}

// ---------------------------------------------------------------------------
// Standalone LayerNorm (for ln2): one block per row. fp32 in -> bf16 out.
// ---------------------------------------------------------------------------
__global__ __launch_bounds__(256) void ln_kernel(
    const float* __restrict__ x, const float* __restrict__ g,
    const float* __restrict__ bt, bf16_t* __restrict__ out)
{
  int row = blockIdx.x;
  int tid = threadIdx.x;
  const float* xr = x + (size_t)row * EMBED;
  float v0 = xr[tid], v1 = xr[tid + 256], v2 = xr[tid + 512];
  float s  = v0 + v1 + v2;
  float s2 = v0*v0 + v1*v1 + v2*v2;
  #pragma unroll
  for (int o = 32; o >= 1; o >>= 1) {
    s  += __shfl_xor(s,  o, 64);
    s2 += __shfl_xor(s2, o, 64);
  }
  __shared__ float red[8];
  int wave = tid >> 6, lane = tid & 63;
  if (lane == 0) { red[wave] = s; red[wave + 4] = s2; }
  __syncthreads();
  s  = red[0] + red[1] + red[2] + red[3];
  s2 = red[4] + red[5] + red[6] + red[7];
  float mu  = s * (1.0f / EMBED);
  float var = s2 * (1.0f / EMBED) - mu * mu;
  float rs  = rsqrtf(var + 1e-5f);
  bf16_t* orow = out + (size_t)row * EMBED;
  orow[tid]       = (bf16_t)((v0 - mu) * rs * g[tid]       + bt[tid]);
  orow[tid + 256] = (bf16_t)((v1 - mu) * rs * g[tid + 256] + bt[tid + 256]);
  orow[tid + 512] = (bf16_t)((v2 - mu) * rs * g[tid + 512] + bt[tid + 512]);
}

// ---------------------------------------------------------------------------
// GEMM: out[M,N] = epi(A[M,K] @ WT[N,K]^T + bias [+res]).  BK=64.
// 128xBN tile, 1D grid, XCD-aware swizzle. global_load_lds staging, XOR-LDS.
// MODE 1: bf16 + tanh-GELU (v*e/(e+1), e=exp(2u)). MODE 2: fp32+residual.
// MODE 3 (qkv): bf16; n<768 scaled by QSCALE; n>=1536 (V) written TRANSPOSED
// into vt[bh][d][l]. MODE 4: split-K=2, fp32 atomicAdd; khalf==0 adds bias.
// ---------------------------------------------------------------------------
template<int MODE, int BN>
__global__ __launch_bounds__(256) void gemm_kernel(
    const bf16_t* __restrict__ A, const bf16_t* __restrict__ WT,
    const float* __restrict__ bias, const float* __restrict__ res,
    void* __restrict__ outp, bf16_t* __restrict__ vt, int N, int K)
{
  constexpr int JT = BN / 32;              // n-subtiles per wave
  __shared__ bf16_t As[128 * 64];
  __shared__ bf16_t Bs[BN * 64];
  int tid = threadIdx.x;
  int lane = tid & 63, wave = tid >> 6;
  int l15 = lane & 15, quad = lane >> 4;
  int wm = wave >> 1, wn = wave & 1;

  int Nn = N / BN;
  int lin = blockIdx.x;
  int khalf = 0, k_lo = 0, k_hi = K;
  if (MODE == 4) { khalf = lin & 1; lin >>= 1; k_lo = khalf * (K / 2); k_hi = k_lo + K / 2; }
  int bm = (lin & 7) + 8 * ((lin >> 3) / Nn);
  int bn = (lin >> 3) % Nn;
  int m0 = bm * 128, n0 = bn * BN;

  f32x4 acc[4][JT];
  #pragma unroll
  for (int i = 0; i < 4; ++i)
    #pragma unroll
    for (int j = 0; j < JT; ++j)
      acc[i][j] = (f32x4){0.f, 0.f, 0.f, 0.f};

  int grow = lane >> 3;                     // 0..7
  int gcol = ((lane & 7) ^ grow) * 8;       // logical chunk for phys slot
  const bf16_t* abase = A  + (size_t)(m0 + wave * 32 + grow) * K + gcol;
  const bf16_t* bbase = WT + (size_t)(n0 + wave * (BN / 4) + grow) * K + gcol;
  int swk = l15 & 7;

  for (int k0 = k_lo; k0 < k_hi; k0 += 64) {
    #pragma unroll
    for (int a = 0; a < 4; ++a)
      gll16(abase + (size_t)a * 8 * K + k0, &As[(wave * 32 + a * 8) * 64]);
    #pragma unroll
    for (int a = 0; a < BN / 32; ++a)
      gll16(bbase + (size_t)a * 8 * K + k0, &Bs[(wave * (BN / 4) + a * 8) * 64]);
    __syncthreads();

    #pragma unroll
    for (int g = 0; g < 2; ++g) {
      bf16x8 af[4], bfr[JT];
      #pragma unroll
      for (int i = 0; i < 4; ++i)
        af[i] = *(const bf16x8*)
            &As[(wm * 64 + i * 16 + l15) * 64 + (((g * 4 + quad) ^ swk) * 8)];
      #pragma unroll
      for (int j = 0; j < JT; ++j)
        bfr[j] = *(const bf16x8*)
            &Bs[(wn * (BN / 2) + j * 16 + l15) * 64 + (((g * 4 + quad) ^ swk) * 8)];
      #pragma unroll
      for (int i = 0; i < 4; ++i)
        #pragma unroll
        for (int j = 0; j < JT; ++j)
          acc[i][j] = mfma16(af[i], bfr[j], acc[i][j]);
    }
    __syncthreads();
  }

  #pragma unroll
  for (int i = 0; i < 4; ++i) {
    int mbase = m0 + wm * 64 + i * 16 + quad * 4;
    #pragma unroll
    for (int j = 0; j < JT; ++j) {
      int n = n0 + wn * (BN / 2) + j * 16 + l15;
      float bn_ = (MODE == 4 && khalf != 0) ? 0.f : bias[n];
      if (MODE == 3 && n >= 1536) {
        // V output -> vt[bh][d][l], packed 4 consecutive l per lane
        int dcol = n - 1536;
        int hh = dcol >> 6, dd = dcol & 63;
        int bsel = mbase >> 11, l = mbase & 2047;
        union { bf16_t b4[4]; uint2 u; } pk;
        #pragma unroll
        for (int r = 0; r < 4; ++r)
          pk.b4[r] = (bf16_t)(acc[i][j][r] + bn_);
        *(uint2*)&vt[(((size_t)bsel * NHEADS + hh) * HD + dd) * SEQ + l] = pk.u;
        continue;
      }
      #pragma unroll
      for (int r = 0; r < 4; ++r) {
        size_t idx = (size_t)(mbase + r) * N + n;
        float v = acc[i][j][r] + bn_;
        if (MODE == 1) {
          // tanh-GELU: v * e/(e+1), e = exp(2*0.79788456*(v+0.044715 v^3))
          float e = fast_exp2(fminf(v * (2.3020807f + 0.10293776f * v * v), 120.f));
          v = v * e * fast_rcp(e + 1.0f);
        }
        if (MODE == 3 && n < 768) v *= QSCALE;
        if (MODE == 2) {
          v += res[idx];
          ((float*)outp)[idx] = v;
        } else if (MODE == 4) {
          atomicAdd((float*)outp + idx, v);
        } else {
          ((bf16_t*)outp)[idx] = (bf16_t)v;
        }
      }
    }
  }
}

// ---------------------------------------------------------------------------
// Flash attention (R8 structure + 2-slot ptile rotation): 128 q-rows/block,
// kv-split waves. Wave w owns kv slice [w*32,w*32+32) of each 128-kv tile.
// K AND V staged to wave-private dbuf LDS via coalesced global_load_lds
// (lesson from R9/R10: divergent per-lane V frag loads are L2-transaction
// bound; coalesced staging wins). vmcnt(8): prefetch stays in flight, no
// barriers in loop. ptile rotates over 2 slots (qi&1) to relax the LDS WAR
// that serializes consecutive qi chains. 3D grid (NO XCD pinning - R10
// showed concentrating divergent traffic on one L2 loses).
// ---------------------------------------------------------------------------
__global__ __launch_bounds__(256, 2) void attn_kernel(
    const bf16_t* __restrict__ qkv, const bf16_t* __restrict__ vt,
    bf16_t* __restrict__ attnout)
{
  // per wave: 2 bufs x (K 2048 | V 2048) = 16KB; + 2 ptile slots x 640
  __attribute__((aligned(16))) __shared__ bf16_t smem[4 * 8192 + 4 * 2 * 640];
  __shared__ float dsumf[4][128];

  int qt = blockIdx.x, h = blockIdx.y, b = blockIdx.z;
  int tid = threadIdx.x;
  int wave = tid >> 6, lane = tid & 63;
  int l15 = lane & 15, quad = lane >> 4;
  int q0 = qt * 128;
  int bh = b * NHEADS + h;

  bf16_t* wbase = smem + wave * 8192;           // [buf][K 2048 | V 2048]
  bf16_t* pt0   = smem + 32768 + wave * 1280;   // 2 slots x [16 q][stride 40]

  // Q B-frags (pre-scaled by QSCALE): n=q=l15, k=d=quad*8+j (+32 frag 1)
  bf16x8 bq[8][2];
  #pragma unroll
  for (int qi = 0; qi < 8; ++qi) {
    const bf16_t* qrow = qkv + (size_t)(b * SEQ + q0 + qi * 16 + l15) * 2304
                             + h * HD + quad * 8;
    bq[qi][0] = *(const bf16x8*)qrow;
    bq[qi][1] = *(const bf16x8*)(qrow + 32);
  }
  // drain Q loads so the in-loop vmcnt(8) tracks only gll16 staging ops
  __asm__ volatile("s_waitcnt vmcnt(0)" ::: "memory");

  f32x4 accO[8][4];
  #pragma unroll
  for (int qi = 0; qi < 8; ++qi)
    #pragma unroll
    for (int t2 = 0; t2 < 4; ++t2)
      accO[qi][t2] = (f32x4){0.f, 0.f, 0.f, 0.f};
  float lpart[8] = {};

  // staging lane mappings (wave-private tiles, coalesced 16B/lane)
  int krow_l = lane >> 3;
  int kchunk = ((lane & 7) ^ krow_l) * 8;
  const bf16_t* ksrc0 = qkv + (size_t)(b * SEQ + wave * 32 + krow_l) * 2304
                            + 768 + h * HD + kchunk;
  int vrow_l = lane >> 2;
  int vchunk = ((lane & 3) ^ (vrow_l & 3)) * 8;
  const bf16_t* vsrc0 = vt + ((size_t)bh * HD + vrow_l) * SEQ + wave * 32 + vchunk;

  constexpr int NIT = SEQ / 128;   // 16

  // prologue: stage tile 0 into buf 0
  {
    bf16_t* kb = wbase;
    bf16_t* vb = wbase + 2048;
    #pragma unroll
    for (int p = 0; p < 4; ++p) {
      gll16(ksrc0 + (size_t)(p * 8) * 2304, kb + p * 512);
      gll16(vsrc0 + (size_t)(p * 16) * SEQ, vb + p * 512);
    }
  }

  int cb = 0;
  for (int it = 0; it < NIT; ++it) {
    // prefetch next tile (wraps on last iter; harmless) into other buffer
    {
      int kvn = ((it + 1) & (NIT - 1)) * 128;
      const bf16_t* ks = ksrc0 + (size_t)kvn * 2304;
      const bf16_t* vs = vsrc0 + kvn;
      bf16_t* kb = wbase + (cb ^ 1) * 4096;
      bf16_t* vb = kb + 2048;
      #pragma unroll
      for (int p = 0; p < 4; ++p) {
        gll16(ks + (size_t)(p * 8) * 2304, kb + p * 512);
        gll16(vs + (size_t)(p * 16) * SEQ, vb + p * 512);
      }
    }
    // wait for CURRENT buffer only (8 newest loads stay in flight)
    __asm__ volatile("s_waitcnt vmcnt(8)" ::: "memory");

    const bf16_t* kb = wbase + cb * 4096;
    const bf16_t* vb = kb + 2048;

    // K A-frags: m=kv=t*16+l15, k=d=(f*4+quad)*8+j ; swizzle phys=c^(l15&7)
    bf16x8 ak[2][2];
    #pragma unroll
    for (int t = 0; t < 2; ++t)
      #pragma unroll
      for (int f = 0; f < 2; ++f)
        ak[t][f] = *(const bf16x8*)
            &kb[(t * 16 + l15) * 64 + (((f * 4 + quad) ^ (l15 & 7)) * 8)];

    // V B-frags: n=d=t2*16+l15, k=kv=quad*8+j ; swizzle phys=quad^(l15&3)
    bf16x8 bv[4];
    #pragma unroll
    for (int t2 = 0; t2 < 4; ++t2)
      bv[t2] = *(const bf16x8*)
          &vb[(t2 * 16 + l15) * 32 + ((quad ^ (l15 & 3)) * 8)];

    #pragma unroll
    for (int qi = 0; qi < 8; ++qi) {
      bf16_t* pt = pt0 + (qi & 1) * 640;    // rotate 2 slots: relax LDS WAR
      #pragma unroll
      for (int t = 0; t < 2; ++t) {
        f32x4 s = (f32x4){0.f, 0.f, 0.f, 0.f};
        s = mfma16(ak[t][0], bq[qi][0], s);   // S^T: (kv=quad*4+r, q=l15)
        s = mfma16(ak[t][1], bq[qi][1], s);
        union { bf16_t b4[4]; uint2 u; } pk;
        float ls = 0.f;
        #pragma unroll
        for (int r = 0; r < 4; ++r) {
          float pv = fast_exp2(s[r]);
          ls += pv;
          pk.b4[r] = (bf16_t)pv;
        }
        lpart[qi] += ls;
        *(uint2*)&pt[l15 * 40 + t * 16 + quad * 4] = pk.u;
      }
      bf16x8 ap = *(const bf16x8*)&pt[l15 * 40 + quad * 8];
      #pragma unroll
      for (int t2 = 0; t2 < 4; ++t2)
        accO[qi][t2] = mfma16(ap, bv[t2], accO[qi][t2]);
    }
    cb ^= 1;
  }

  // denominators: lane holds partial for q=l15 over this wave's kv slices
  #pragma unroll
  for (int qi = 0; qi < 8; ++qi) {
    float l = lpart[qi];
    l += __shfl_xor(l, 16, 64);
    l += __shfl_xor(l, 32, 64);
    if (quad == 0) dsumf[wave][qi * 16 + l15] = l;
  }
  __syncthreads();   // waves done with private tiles; dsumf published

  float* slabf = (float*)smem;   // 4 slabs x 2048 f32 = 32 KB (K/V dbuf region)
  int rq = lane >> 3;            // 0..7
  int d0 = (lane & 7) * 8;

  for (int pass = 0; pass < 4; ++pass) {
    #pragma unroll
    for (int qi2 = 0; qi2 < 2; ++qi2) {
      int qi = pass * 2 + qi2;
      #pragma unroll
      for (int t2 = 0; t2 < 4; ++t2)
        #pragma unroll
        for (int r = 0; r < 4; ++r)
          slabf[wave * 2048 + (qi2 * 16 + quad * 4 + r) * 64 + t2 * 16 + l15]
              = accO[qi][t2][r];
    }
    __syncthreads();
    int q_loc = wave * 8 + rq;
    f32x4 o0 = (f32x4){0.f,0.f,0.f,0.f}, o1 = (f32x4){0.f,0.f,0.f,0.f};
    #pragma unroll
    for (int sw = 0; sw < 4; ++sw) {
      o0 += *(const f32x4*)&slabf[sw * 2048 + q_loc * 64 + d0];
      o1 += *(const f32x4*)&slabf[sw * 2048 + q_loc * 64 + d0 + 4];
    }
    int q_abs = pass * 32 + q_loc;
    float den = dsumf[0][q_abs] + dsumf[1][q_abs] + dsumf[2][q_abs] + dsumf[3][q_abs];
    float inv = 1.0f / den;
    bf16_t ob[8];
    #pragma unroll
    for (int j = 0; j < 4; ++j) {
      ob[j]     = (bf16_t)(o0[j] * inv);
      ob[j + 4] = (bf16_t)(o1[j] * inv);
    }
    *(uint4*)&attnout[(size_t)(b * SEQ + q0 + q_abs) * EMBED + h * HD + d0]
        = *(const uint4*)ob;
    if (pass < 3) __syncthreads();
  }
}

// ---------------------------------------------------------------------------
extern "C" void kernel_launch(void* const* d_in, const int* in_sizes, int n_in,
                              void* d_out, int out_size, void* d_ws, size_t ws_size,
                              hipStream_t stream) {
  (void)in_sizes; (void)n_in; (void)out_size; (void)ws_size;
  const float* x      = (const float*)d_in[0];
  const float* ln1_g  = (const float*)d_in[1];
  const float* ln1_b  = (const float*)d_in[2];
  const float* qkv_w  = (const float*)d_in[3];
  const float* qkv_b  = (const float*)d_in[4];
  const float* proj_w = (const float*)d_in[5];
  const float* proj_b = (const float*)d_in[6];
  const float* ln2_g  = (const float*)d_in[7];
  const float* ln2_b  = (const float*)d_in[8];
  const float* fc1_w  = (const float*)d_in[9];
  const float* fc1_b  = (const float*)d_in[10];
  const float* fc2_w  = (const float*)d_in[11];
  const float* fc2_b  = (const float*)d_in[12];
  float* out = (float*)d_out;

  char* p = (char*)d_ws;
  bf16_t* wqkvT  = (bf16_t*)p; p += (size_t)2304 * 768 * 2;
  bf16_t* wprojT = (bf16_t*)p; p += (size_t)768 * 768 * 2;
  bf16_t* wfc1T  = (bf16_t*)p; p += (size_t)3072 * 768 * 2;
  bf16_t* wfc2T  = (bf16_t*)p; p += (size_t)768 * 3072 * 2;
  bf16_t* hbuf   = (bf16_t*)p; p += (size_t)ROWS * 768 * 2;
  bf16_t* qkv    = (bf16_t*)p;          // dead after attention
  bf16_t* hid    = (bf16_t*)p; p += (size_t)ROWS * 3072 * 2;  // aliases qkv
  bf16_t* vt     = (bf16_t*)p; p += (size_t)BATCH * NHEADS * HD * SEQ * 2;
  bf16_t* attno  = (bf16_t*)p; p += (size_t)ROWS * 768 * 2;

  // weight prep + LN1 (one launch; no static state allowed)
  prep_kernel<<<6912 + ROWS, 256, 0, stream>>>(
      qkv_w, wqkvT, proj_w, wprojT, fc1_w, wfc1T, fc2_w, wfc2T,
      x, ln1_g, ln1_b, hbuf);

  // attention sublayer (qkv GEMM writes V directly transposed into vt)
  gemm_kernel<3,128><<<32 * (2304/128), 256, 0, stream>>>(
      hbuf, wqkvT, qkv_b, nullptr, qkv, vt, 2304, 768);
  attn_kernel<<<dim3(SEQ/128, NHEADS, BATCH), 256, 0, stream>>>(qkv, vt, attno);
  gemm_kernel<2,64><<<32 * (768/64), 256, 0, stream>>>(
      attno, wprojT, proj_b, x, out, nullptr, 768, 768);

  // FFN sublayer
  ln_kernel<<<ROWS, 256, 0, stream>>>(out, ln2_g, ln2_b, hbuf);
  gemm_kernel<1,128><<<32 * (3072/128), 256, 0, stream>>>(
      hbuf, wfc1T, fc1_b, nullptr, hid, nullptr, 3072, 768);
  gemm_kernel<4,64><<<2 * 32 * (768/64), 256, 0, stream>>>(
      hid, wfc2T, fc2_b, nullptr, out, nullptr, 768, 3072);
}